// Round 1
// baseline (140.897 us; speedup 1.0000x reference)
//
#include <hip/hip_runtime.h>
#include <math.h>

// TopKMoEGate: T = 16384, D = 1024, E = 64, topK = 2.
// Round 6: fused single-pass kernel.
//  - rocprof showed 256-MiB harness poison fills (~42 us each) dominate GPU
//    time; our kernels are each <41 us. Attack the controllable part:
//    (1) kill the 33.6 MB split-K partial round-trip + reduce kernel,
//    (2) kill the per-cc double-barrier + vmcnt(0) drain (B image is 384 KB,
//        L2-resident -> load fragments straight to VGPRs, no LDS staging),
//    (3) one kernel launch instead of two dependent ones.
//  - Block = 16 tokens, 4 waves; wave w computes expert tile [16w..16w+15]
//    over full K=1024 (16 k64-chunks). A converted per-wave (4x duplicate
//    VALU, hidden under loads); B coalesced dwordx4 from pre-permuted image.
//  - Epilogue: one __syncthreads, 4 KB LDS transpose, then round-3-verified
//    lane=expert butterfly top-2 + sparse softmax, written inline.

#define DDIM 1024
#define NEXP 64
#define NTOK 16384

typedef float f4 __attribute__((ext_vector_type(4)));
typedef short s8 __attribute__((ext_vector_type(8)));
typedef unsigned int u32;

static __device__ __forceinline__ void split3(float f, short& h, short& m, short& l) {
    const u32 uf = __float_as_uint(f);
    h = (short)(uf >> 16);
    const float r1 = f - __uint_as_float(uf & 0xffff0000u);
    const u32 u1 = __float_as_uint(r1);
    m = (short)(u1 >> 16);
    const float r2 = r1 - __uint_as_float(u1 & 0xffff0000u);
    l = (short)(__float_as_uint(r2) >> 16);
}

// ---- kernel 0: slice gate_w into 3 bf16 levels, lane-ordered image ----
// unit16 U'(c,kk,lv,t,q,m) = c*1536 + (kk*3+lv)*256 + t*64 + q*16 + m,
// holding w[e=t*16+m][k0..k0+7], k0 = c*64 + kk*32 + q*8.
__global__ __launch_bounds__(256)
void w_prep(const float* __restrict__ gw, short* __restrict__ wimg) {
    const int uid = blockIdx.x * 256 + threadIdx.x;   // 8192 threads
    const int c   = uid >> 9;
    const int kk  = (uid >> 8) & 1;
    const int e   = (uid >> 2) & 63;
    const int q   = uid & 3;
    const int k0  = c * 64 + kk * 32 + q * 8;
    const float* src = gw + (size_t)e * DDIM + k0;
    s8 hv, mv, lv;
    #pragma unroll
    for (int j = 0; j < 8; ++j) {
        short h, m, l;
        split3(src[j], h, m, l);
        hv[j] = h; mv[j] = m; lv[j] = l;
    }
    const size_t base = (size_t)c * 1536 + (kk * 3) * 256
                      + (e >> 4) * 64 + q * 16 + (e & 15);
    *(s8*)(wimg + (base      ) * 8) = hv;
    *(s8*)(wimg + (base + 256) * 8) = mv;
    *(s8*)(wimg + (base + 512) * 8) = lv;
}

// ---- kernel 1: fused GEMM + noisy top-2 + sparse softmax ----
__global__ __launch_bounds__(256, 3)
void gate_fused(const float* __restrict__ x,
                const short* __restrict__ wimg,
                const float* __restrict__ noise_weight,
                const float* __restrict__ noise,
                float* __restrict__ out_w,
                float* __restrict__ out_i)
{
    __shared__ float L[16][66];                 // [token][expert], padded

    const int tid  = threadIdx.x;
    const int lane = tid & 63;
    const int wv   = tid >> 6;                  // expert tile t = wv
    const int m    = lane & 15;
    const int q    = lane >> 4;
    const int tokBase = blockIdx.x * 16;

    const float* xrow = x + (size_t)(tokBase + m) * DDIM + q * 8;
    const short* wb   = wimg + ((size_t)wv * 64 + lane) * 8;

    f4 acc0 = (f4)0.f, acc1 = (f4)0.f;

    // A register double-buffer, depth-1 prefetch
    f4 sa[2][4];
    sa[0][0] = *(const f4*)(xrow);
    sa[0][1] = *(const f4*)(xrow + 4);
    sa[0][2] = *(const f4*)(xrow + 32);
    sa[0][3] = *(const f4*)(xrow + 36);

    #pragma unroll 2
    for (int cc = 0; cc < 16; ++cc) {
        const int cur = cc & 1;

        // B fragments for this chunk: straight from L2-resident image,
        // coalesced 1 KB per instruction. Issue before convert so the
        // ~200cy L2 latency hides under the split3 VALU work.
        const short* p = wb + (size_t)cc * (1536 * 8);
        const s8 bh0 = *(const s8*)(p);
        const s8 bm0 = *(const s8*)(p +  256 * 8);
        const s8 bl0 = *(const s8*)(p +  512 * 8);
        const s8 bh1 = *(const s8*)(p +  768 * 8);
        const s8 bm1 = *(const s8*)(p + 1024 * 8);
        const s8 bl1 = *(const s8*)(p + 1280 * 8);

        // prefetch next A chunk (HBM)
        if (cc + 1 < 16) {
            const float* s = xrow + (cc + 1) * 64;
            sa[cur ^ 1][0] = *(const f4*)(s);
            sa[cur ^ 1][1] = *(const f4*)(s + 4);
            sa[cur ^ 1][2] = *(const f4*)(s + 32);
            sa[cur ^ 1][3] = *(const f4*)(s + 36);
        }

        // convert current A chunk -> 3-level bf16 frags
        s8 ah[2], am_[2], al[2];
        const float* sv = (const float*)sa[cur];
        #pragma unroll
        for (int kk = 0; kk < 2; ++kk)
            #pragma unroll
            for (int j = 0; j < 8; ++j) {
                short h, mm, l;
                split3(sv[kk * 8 + j], h, mm, l);
                ah[kk][j] = h; am_[kk][j] = mm; al[kk][j] = l;
            }

        // 12 MFMAs: hh -> acc0; cross terms -> acc1 (err ~2^-24)
        acc0 = __builtin_amdgcn_mfma_f32_16x16x32_bf16(ah[0], bh0, acc0, 0, 0, 0);
        acc1 = __builtin_amdgcn_mfma_f32_16x16x32_bf16(ah[0], bm0, acc1, 0, 0, 0);
        acc1 = __builtin_amdgcn_mfma_f32_16x16x32_bf16(am_[0], bh0, acc1, 0, 0, 0);
        acc1 = __builtin_amdgcn_mfma_f32_16x16x32_bf16(ah[0], bl0, acc1, 0, 0, 0);
        acc1 = __builtin_amdgcn_mfma_f32_16x16x32_bf16(am_[0], bm0, acc1, 0, 0, 0);
        acc1 = __builtin_amdgcn_mfma_f32_16x16x32_bf16(al[0], bh0, acc1, 0, 0, 0);

        acc0 = __builtin_amdgcn_mfma_f32_16x16x32_bf16(ah[1], bh1, acc0, 0, 0, 0);
        acc1 = __builtin_amdgcn_mfma_f32_16x16x32_bf16(ah[1], bm1, acc1, 0, 0, 0);
        acc1 = __builtin_amdgcn_mfma_f32_16x16x32_bf16(am_[1], bh1, acc1, 0, 0, 0);
        acc1 = __builtin_amdgcn_mfma_f32_16x16x32_bf16(ah[1], bl1, acc1, 0, 0, 0);
        acc1 = __builtin_amdgcn_mfma_f32_16x16x32_bf16(am_[1], bm1, acc1, 0, 0, 0);
        acc1 = __builtin_amdgcn_mfma_f32_16x16x32_bf16(al[1], bh1, acc1, 0, 0, 0);
    }

    // C layout (round-4/5-verified): lane(q,m), reg r ->
    //   logit[token = tokBase + q*4 + r][expert = m + 16*wv]
    #pragma unroll
    for (int r = 0; r < 4; ++r)
        L[q * 4 + r][m + 16 * wv] = acc0[r] + acc1[r];
    __syncthreads();

    // wave wv handles tokens wv*4 .. wv*4+3; lane = expert (r3-verified)
    const float nw = noise_weight[lane];
    #pragma unroll
    for (int tt = 0; tt < 4; ++tt) {
        const int tok  = wv * 4 + tt;
        const int gtok = tokBase + tok;
        const float ln = fmaf(noise[(size_t)gtok * NEXP + lane], nw, L[tok][lane]);

        float v1 = ln; int i1 = lane;
        #pragma unroll
        for (int off = 32; off > 0; off >>= 1) {
            const float vo = __shfl_xor(v1, off, 64);
            const int   io = __shfl_xor(i1, off, 64);
            if (vo > v1 || (vo == v1 && io < i1)) { v1 = vo; i1 = io; }
        }
        float v2 = (lane == i1) ? -3.4e38f : ln; int i2 = lane;
        #pragma unroll
        for (int off = 32; off > 0; off >>= 1) {
            const float vo = __shfl_xor(v2, off, 64);
            const int   io = __shfl_xor(i2, off, 64);
            if (vo > v2 || (vo == v2 && io < i2)) { v2 = vo; i2 = io; }
        }

        const float d   = expf(v2 - v1);
        const float inv = 1.f / (1.f + d);
        const float wgt = (lane == i1) ? inv : ((lane == i2) ? d * inv : 0.f);
        out_w[(size_t)gtok * NEXP + lane] = wgt;
        if (lane == 0) {
            out_i[(size_t)gtok * 2]     = (float)i1;
            out_i[(size_t)gtok * 2 + 1] = (float)i2;
        }
    }
}

extern "C" void kernel_launch(void* const* d_in, const int* in_sizes, int n_in,
                              void* d_out, int out_size, void* d_ws, size_t ws_size,
                              hipStream_t stream) {
    const float* x     = (const float*)d_in[0];
    const float* gw    = (const float*)d_in[1];
    const float* nwt   = (const float*)d_in[2];
    const float* noise = (const float*)d_in[3];
    float* out_w = (float*)d_out;                        // [NTOK][64]
    float* out_i = (float*)d_out + (size_t)NTOK * NEXP;  // [NTOK][2] as float

    short* wimg = (short*)d_ws;                          // 384 KB image

    hipLaunchKernelGGL(w_prep, dim3(32), dim3(256), 0, stream, gw, wimg);
    hipLaunchKernelGGL(gate_fused, dim3(NTOK / 16), dim3(256), 0, stream,
                       x, wimg, nwt, noise, out_w, out_i);
}